// Round 1
// baseline (2064.728 us; speedup 1.0000x reference)
//
#include <hip/hip_runtime.h>
#include <hip/hip_bf16.h>

#define WIN 7
#define DISPL 3
#define NHEADS 6
#define HD 32
#define HH 224
#define WWID 224
#define NB 2
#define MROWS (NB*HH*WWID)   // 100352

typedef __attribute__((ext_vector_type(8))) short short8v;
typedef __attribute__((ext_vector_type(4))) float f32x4;

__device__ __forceinline__ float b2f(unsigned short u) {
    unsigned v = ((unsigned)u) << 16;
    return __builtin_bit_cast(float, v);
}
__device__ __forceinline__ unsigned short f2b(float f) {
    unsigned u = __builtin_bit_cast(unsigned, f);
    unsigned r = (u + 0x7FFFu + ((u >> 16) & 1u)) >> 16;
    return (unsigned short)r;
}

// ---------------- weight convert + transpose: W[K][N] f32 -> Wt[N][K] bf16 ---
__global__ void wt_k(const float* __restrict__ W, unsigned short* __restrict__ Wt,
                     int Kk, int Nn) {
    int idx = blockIdx.x * 256 + threadIdx.x;
    if (idx >= Kk * Nn) return;
    int n = idx % Nn, k = idx / Nn;
    Wt[(size_t)n * Kk + k] = f2b(W[idx]);
}

// ---------------- unfold: x[2][96][448][448] -> U[M][384] bf16 ---------------
__global__ __launch_bounds__(192) void unfold_k(const float* __restrict__ x,
                                                unsigned short* __restrict__ U) {
    int blk = blockIdx.x;          // 2*224*4
    int chunk = blk & 3; int bi = blk >> 2;   // bi = b*224 + i
    int t = threadIdx.x;           // 0..191
    int c = t >> 1, p1 = t & 1;
    int b = bi / 224, i = bi % 224;
    const float* xr = x + (((size_t)b * 96 + c) * 448 + 2 * i + p1) * 448;
    unsigned short* Ub = U + ((size_t)bi * 224) * 384 + t * 2;
    for (int j = chunk * 56; j < chunk * 56 + 56; j++) {
        float2 xv = *(const float2*)(xr + 2 * j);
        ushort2 o; o.x = f2b(xv.x); o.y = f2b(xv.y);
        *(ushort2*)(Ub + (size_t)j * 384) = o;
    }
}

// ---------------- layernorm: t[M][192] f32 -> y[M][192] bf16 -----------------
__global__ __launch_bounds__(256) void ln_k(const float* __restrict__ x,
                                            const float* __restrict__ g,
                                            const float* __restrict__ bta,
                                            unsigned short* __restrict__ y) {
    int row = blockIdx.x * 4 + (threadIdx.x >> 6);
    int lane = threadIdx.x & 63;
    const float* xr = x + (size_t)row * 192;
    float v0 = xr[lane], v1 = xr[lane + 64], v2 = xr[lane + 128];
    float s = v0 + v1 + v2, sq = v0 * v0 + v1 * v1 + v2 * v2;
    #pragma unroll
    for (int o = 32; o > 0; o >>= 1) { s += __shfl_xor(s, o); sq += __shfl_xor(sq, o); }
    float mean = s * (1.f / 192.f);
    float var = sq * (1.f / 192.f) - mean * mean;
    float rs = rsqrtf(var + 1e-5f);
    unsigned short* yr = y + (size_t)row * 192;
    yr[lane]       = f2b((v0 - mean) * rs * g[lane]       + bta[lane]);
    yr[lane + 64]  = f2b((v1 - mean) * rs * g[lane + 64]  + bta[lane + 64]);
    yr[lane + 128] = f2b((v2 - mean) * rs * g[lane + 128] + bta[lane + 128]);
}

// ---------------- GEMM: C[M][N] = A[M][K](bf16) * Bt[N][K](bf16) + epi -------
template<int BIAS, int RES, int GELU, int OBF16>
__global__ __launch_bounds__(256) void gemm_k(const unsigned short* __restrict__ A,
                                              const unsigned short* __restrict__ Bt,
                                              const float* __restrict__ bias,
                                              const float* __restrict__ resid,
                                              void* __restrict__ Cout,
                                              int Nn, int Kk) {
    __shared__ unsigned short Asm[64 * 40];
    __shared__ unsigned short Bsm[64 * 40];
    int t = threadIdx.x;
    int n0 = blockIdx.x * 64, m0 = blockIdx.y * 64;
    int lane = t & 63, w = t >> 6;
    int wrow = w >> 1, wcol = w & 1;
    f32x4 acc[2][2] = {};
    int arow = t >> 2, aseg = t & 3;
    const unsigned short* Aptr = A + (size_t)(m0 + arow) * Kk + aseg * 8;
    const unsigned short* Bptr = Bt + (size_t)(n0 + arow) * Kk + aseg * 8;
    int k8 = lane >> 4, r16 = lane & 15;
    for (int k0 = 0; k0 < Kk; k0 += 32) {
        uint4 av = *(const uint4*)(Aptr + k0);
        uint4 bv = *(const uint4*)(Bptr + k0);
        __syncthreads();
        *(uint4*)&Asm[arow * 40 + aseg * 8] = av;
        *(uint4*)&Bsm[arow * 40 + aseg * 8] = bv;
        __syncthreads();
        short8v a0 = *(const short8v*)&Asm[(wrow * 32 + r16) * 40 + k8 * 8];
        short8v a1 = *(const short8v*)&Asm[(wrow * 32 + 16 + r16) * 40 + k8 * 8];
        short8v b0 = *(const short8v*)&Bsm[(wcol * 32 + r16) * 40 + k8 * 8];
        short8v b1 = *(const short8v*)&Bsm[(wcol * 32 + 16 + r16) * 40 + k8 * 8];
        acc[0][0] = __builtin_amdgcn_mfma_f32_16x16x32_bf16(a0, b0, acc[0][0], 0, 0, 0);
        acc[0][1] = __builtin_amdgcn_mfma_f32_16x16x32_bf16(a0, b1, acc[0][1], 0, 0, 0);
        acc[1][0] = __builtin_amdgcn_mfma_f32_16x16x32_bf16(a1, b0, acc[1][0], 0, 0, 0);
        acc[1][1] = __builtin_amdgcn_mfma_f32_16x16x32_bf16(a1, b1, acc[1][1], 0, 0, 0);
    }
    int q = lane >> 4;
    #pragma unroll
    for (int mi = 0; mi < 2; mi++)
    #pragma unroll
    for (int ni = 0; ni < 2; ni++) {
        int col = n0 + wcol * 32 + ni * 16 + r16;
        #pragma unroll
        for (int r = 0; r < 4; r++) {
            int row = m0 + wrow * 32 + mi * 16 + q * 4 + r;
            float v = acc[mi][ni][r];
            if (BIAS) v += bias[col];
            if (RES) v += resid[(size_t)row * Nn + col];
            if (GELU) v = 0.5f * v * (1.0f + erff(v * 0.70710678118654752f));
            if (OBF16) ((unsigned short*)Cout)[(size_t)row * Nn + col] = f2b(v);
            else       ((float*)Cout)[(size_t)row * Nn + col] = v;
        }
    }
}

// ---------------- window attention ------------------------------------------
// qkv [M][576] bf16 (layout s*192 + head*32 + d), out ao [M][192] bf16
template<int SHIFT>
__global__ __launch_bounds__(256) void attn_k(const unsigned short* __restrict__ qkv,
                                              const float* __restrict__ pos,
                                              unsigned short* __restrict__ ao) {
    __shared__ float Qs[49 * 33], Ks[49 * 33], Vs[49 * 33], Pl[169];
    int bidx = blockIdx.x;
    int head = bidx % NHEADS;
    int w = bidx / NHEADS;
    int b = w >> 10;            // 1024 windows per image
    int wrem = w & 1023;
    int wi = wrem >> 5, wj = wrem & 31;
    int t = threadIdx.x;
    for (int cidx = t; cidx < 49 * 12; cidx += 256) {
        int p = cidx / 12, rest = cidx % 12;
        int s = rest >> 2, q8 = rest & 3;
        int pi = p / 7, pj = p % 7;
        int gi = wi * 7 + pi, gj = wj * 7 + pj;
        if (SHIFT) { gi = (gi + DISPL) % HH; gj = (gj + DISPL) % WWID; }
        size_t m = ((size_t)b * HH + gi) * WWID + gj;
        uint4 vv = *(const uint4*)(qkv + m * 576 + s * 192 + head * 32 + q8 * 8);
        const unsigned short* us = (const unsigned short*)&vv;
        float* dst = (s == 0 ? Qs : (s == 1 ? Ks : Vs)) + p * 33 + q8 * 8;
        #pragma unroll
        for (int e = 0; e < 8; e++) dst[e] = b2f(us[e]);
    }
    for (int i = t; i < 169; i += 256) Pl[i] = pos[i];
    __syncthreads();
    int wave = t >> 6, lane = t & 63;
    int jh = lane / 7, jw = lane % 7;
    const float scale = 0.17677669529663687f;
    for (int i = wave; i < 49; i += 4) {
        int ih = i / 7, iw = i % 7;
        float s;
        if (lane < 49) {
            float acc = 0.f;
            #pragma unroll
            for (int d = 0; d < 32; d++) acc += Qs[i * 33 + d] * Ks[lane * 33 + d];
            s = acc * scale + Pl[(jh - ih + 6) * 13 + (jw - iw + 6)];
            if (SHIFT) {
                bool msk = false;
                if (wi == 31) msk = msk || ((i >= 28) != (lane >= 28));
                if (wj == 31) msk = msk || ((iw >= 4) != (jw >= 4));
                if (msk) s = -1e30f;
            }
        } else s = -1e30f;
        float mx = s;
        #pragma unroll
        for (int o = 32; o > 0; o >>= 1) mx = fmaxf(mx, __shfl_xor(mx, o));
        float p = (lane < 49) ? __expf(s - mx) : 0.f;
        float sum = p;
        #pragma unroll
        for (int o = 32; o > 0; o >>= 1) sum += __shfl_xor(sum, o);
        p /= sum;
        float acc = 0.f;
        int d = lane & 31;
        for (int j = 0; j < 49; j++) {
            float pj = __shfl(p, j);
            acc += pj * Vs[j * 33 + d];
        }
        if (lane < 32) {
            int gi = wi * 7 + ih, gj = wj * 7 + iw;
            if (SHIFT) { gi = (gi + DISPL) % HH; gj = (gj + DISPL) % WWID; }
            size_t m = ((size_t)b * HH + gi) * WWID + gj;
            ao[m * 192 + head * 32 + d] = f2b(acc);
        }
    }
}

// ---------------- final transpose: t[2][224][224][192] -> out[2][192][224][224]
__global__ __launch_bounds__(256) void tr_k(const float* __restrict__ tin,
                                            float* __restrict__ outp) {
    __shared__ float tile[32][33];
    int bi = blockIdx.x;                  // b*224 + i
    int j0 = blockIdx.y * 32, c0 = blockIdx.z * 32;
    int t = threadIdx.x;
    int tx = t & 31, ty = t >> 5;
    int b = bi / 224, i = bi % 224;
    #pragma unroll
    for (int yy = 0; yy < 32; yy += 8) {
        int j = j0 + ty + yy;
        tile[ty + yy][tx] = tin[((size_t)bi * 224 + j) * 192 + c0 + tx];
    }
    __syncthreads();
    #pragma unroll
    for (int yy = 0; yy < 32; yy += 8) {
        int c = c0 + ty + yy;
        outp[(((size_t)b * 192 + c) * 224 + i) * 224 + j0 + tx] = tile[tx][ty + yy];
    }
}

extern "C" void kernel_launch(void* const* d_in, const int* in_sizes, int n_in,
                              void* d_out, int out_size, void* d_ws, size_t ws_size,
                              hipStream_t stream) {
    (void)in_sizes; (void)n_in; (void)out_size; (void)ws_size;
    const float* x    = (const float*)d_in[0];
    const float* pm_w = (const float*)d_in[1];
    const float* pm_b = (const float*)d_in[2];

    const size_t M = MROWS;
    char* ws = (char*)d_ws;
    size_t off = 0;
    float* tbuf = (float*)(ws + off);           off += M * 192 * 4;   // 77.07 MB
    unsigned short* ybuf = (unsigned short*)(ws + off); off += M * 192 * 2; // 38.5 MB
    unsigned short* big  = (unsigned short*)(ws + off); off += M * 768 * 2; // 154 MB (U / qkv / h)
    unsigned short* pm_wt = (unsigned short*)(ws + off); off += 192 * 384 * 2;
    unsigned short* wqkv_t[2]; unsigned short* wo_t[2];
    unsigned short* w1_t[2];   unsigned short* w2_t[2];
    for (int s = 0; s < 2; s++) {
        wqkv_t[s] = (unsigned short*)(ws + off); off += 576 * 192 * 2;
        wo_t[s]   = (unsigned short*)(ws + off); off += 192 * 192 * 2;
        w1_t[s]   = (unsigned short*)(ws + off); off += 768 * 192 * 2;
        w2_t[s]   = (unsigned short*)(ws + off); off += 192 * 768 * 2;
    }
    unsigned short* U   = big;              // [M][384]
    unsigned short* qkv = big;              // [M][576]
    unsigned short* hbf = big;              // [M][768]
    unsigned short* ao  = ybuf;             // aliases y (y dead when attn writes)

    auto wt = [&](const float* W, unsigned short* Wt, int K, int N) {
        int n = K * N;
        wt_k<<<(n + 255) / 256, 256, 0, stream>>>(W, Wt, K, N);
    };
    wt(pm_w, pm_wt, 384, 192);
    for (int s = 0; s < 2; s++) {
        wt((const float*)d_in[5 + 12 * s],  wqkv_t[s], 192, 576);
        wt((const float*)d_in[7 + 12 * s],  wo_t[s],   192, 192);
        wt((const float*)d_in[11 + 12 * s], w1_t[s],   192, 768);
        wt((const float*)d_in[13 + 12 * s], w2_t[s],   768, 192);
    }

    unfold_k<<<NB * 224 * 4, 192, 0, stream>>>(x, U);
    // t = U @ pm_w + pm_b
    gemm_k<1, 0, 0, 0><<<dim3(3, MROWS / 64), 256, 0, stream>>>(U, pm_wt, pm_b, nullptr, tbuf, 192, 384);

    for (int s = 0; s < 2; s++) {
        const float* ln1g = (const float*)d_in[3 + 12 * s];
        const float* ln1b = (const float*)d_in[4 + 12 * s];
        const float* pos  = (const float*)d_in[6 + 12 * s];
        const float* bo   = (const float*)d_in[8 + 12 * s];
        const float* ln2g = (const float*)d_in[9 + 12 * s];
        const float* ln2b = (const float*)d_in[10 + 12 * s];
        const float* b1   = (const float*)d_in[12 + 12 * s];
        const float* b2   = (const float*)d_in[14 + 12 * s];

        ln_k<<<MROWS / 4, 256, 0, stream>>>(tbuf, ln1g, ln1b, ybuf);
        gemm_k<0, 0, 0, 1><<<dim3(9, MROWS / 64), 256, 0, stream>>>(ybuf, wqkv_t[s], nullptr, nullptr, qkv, 576, 192);
        if (s == 0) attn_k<0><<<2048 * NHEADS, 256, 0, stream>>>(qkv, pos, ao);
        else        attn_k<1><<<2048 * NHEADS, 256, 0, stream>>>(qkv, pos, ao);
        gemm_k<1, 1, 0, 0><<<dim3(3, MROWS / 64), 256, 0, stream>>>(ao, wo_t[s], bo, tbuf, tbuf, 192, 192);
        ln_k<<<MROWS / 4, 256, 0, stream>>>(tbuf, ln2g, ln2b, ybuf);
        gemm_k<1, 0, 1, 1><<<dim3(12, MROWS / 64), 256, 0, stream>>>(ybuf, w1_t[s], b1, nullptr, hbf, 768, 192);
        gemm_k<1, 1, 0, 0><<<dim3(3, MROWS / 64), 256, 0, stream>>>(hbf, w2_t[s], b2, tbuf, tbuf, 192, 768);
    }

    tr_k<<<dim3(NB * 224, 7, 6), 256, 0, stream>>>(tbuf, (float*)d_out);
}

// Round 2
// 950.542 us; speedup vs baseline: 2.1722x; 2.1722x over previous
//
#include <hip/hip_runtime.h>
#include <hip/hip_bf16.h>

#define WIN 7
#define DISPL 3
#define NHEADS 6
#define HD 32
#define HH 224
#define WWID 224
#define NB 2
#define MROWS (NB*HH*WWID)   // 100352

typedef __attribute__((ext_vector_type(8))) short short8v;
typedef __attribute__((ext_vector_type(4))) float f32x4;

__device__ __forceinline__ float b2f(unsigned short u) {
    unsigned v = ((unsigned)u) << 16;
    return __builtin_bit_cast(float, v);
}
__device__ __forceinline__ unsigned short f2b(float f) {
    unsigned u = __builtin_bit_cast(unsigned, f);
    unsigned r = (u + 0x7FFFu + ((u >> 16) & 1u)) >> 16;
    return (unsigned short)r;
}

// ---------------- weight convert + transpose: W[K][N] f32 -> Wt[N][K] bf16 ---
__global__ void wt_k(const float* __restrict__ W, unsigned short* __restrict__ Wt,
                     int Kk, int Nn) {
    int idx = blockIdx.x * 256 + threadIdx.x;
    if (idx >= Kk * Nn) return;
    int n = idx % Nn, k = idx / Nn;
    Wt[(size_t)n * Kk + k] = f2b(W[idx]);
}

// ---------------- unfold: x[2][96][448][448] -> U[M][384] bf16 ---------------
__global__ __launch_bounds__(192) void unfold_k(const float* __restrict__ x,
                                                unsigned short* __restrict__ U) {
    int blk = blockIdx.x;          // 2*224*4
    int chunk = blk & 3; int bi = blk >> 2;   // bi = b*224 + i
    int t = threadIdx.x;           // 0..191
    int c = t >> 1, p1 = t & 1;
    int b = bi / 224, i = bi % 224;
    const float* xr = x + (((size_t)b * 96 + c) * 448 + 2 * i + p1) * 448;
    unsigned short* Ub = U + ((size_t)bi * 224) * 384 + t * 2;
    for (int j = chunk * 56; j < chunk * 56 + 56; j++) {
        float2 xv = *(const float2*)(xr + 2 * j);
        ushort2 o; o.x = f2b(xv.x); o.y = f2b(xv.y);
        *(ushort2*)(Ub + (size_t)j * 384) = o;
    }
}

// ---------------- layernorm: t[M][192] f32 -> y[M][192] bf16 -----------------
__global__ __launch_bounds__(256) void ln_k(const float* __restrict__ x,
                                            const float* __restrict__ g,
                                            const float* __restrict__ bta,
                                            unsigned short* __restrict__ y) {
    int row = blockIdx.x * 4 + (threadIdx.x >> 6);
    int lane = threadIdx.x & 63;
    const float* xr = x + (size_t)row * 192;
    float v0 = xr[lane], v1 = xr[lane + 64], v2 = xr[lane + 128];
    float s = v0 + v1 + v2, sq = v0 * v0 + v1 * v1 + v2 * v2;
    #pragma unroll
    for (int o = 32; o > 0; o >>= 1) { s += __shfl_xor(s, o); sq += __shfl_xor(sq, o); }
    float mean = s * (1.f / 192.f);
    float var = sq * (1.f / 192.f) - mean * mean;
    float rs = rsqrtf(var + 1e-5f);
    unsigned short* yr = y + (size_t)row * 192;
    yr[lane]       = f2b((v0 - mean) * rs * g[lane]       + bta[lane]);
    yr[lane + 64]  = f2b((v1 - mean) * rs * g[lane + 64]  + bta[lane + 64]);
    yr[lane + 128] = f2b((v2 - mean) * rs * g[lane + 128] + bta[lane + 128]);
}

// ---------------- GEMM: C[M][N] = A[M][K](bf16) * Bt[N][K](bf16) + epi -------
template<int BIAS, int RES, int GELU, int OBF16>
__global__ __launch_bounds__(256) void gemm_k(const unsigned short* __restrict__ A,
                                              const unsigned short* __restrict__ Bt,
                                              const float* __restrict__ bias,
                                              const float* __restrict__ resid,
                                              void* __restrict__ Cout,
                                              int Nn, int Kk) {
    __shared__ unsigned short Asm[64 * 40];
    __shared__ unsigned short Bsm[64 * 40];
    int t = threadIdx.x;
    int n0 = blockIdx.x * 64, m0 = blockIdx.y * 64;
    int lane = t & 63, w = t >> 6;
    int wrow = w >> 1, wcol = w & 1;
    f32x4 acc[2][2] = {};
    int arow = t >> 2, aseg = t & 3;
    const unsigned short* Aptr = A + (size_t)(m0 + arow) * Kk + aseg * 8;
    const unsigned short* Bptr = Bt + (size_t)(n0 + arow) * Kk + aseg * 8;
    int k8 = lane >> 4, r16 = lane & 15;
    for (int k0 = 0; k0 < Kk; k0 += 32) {
        uint4 av = *(const uint4*)(Aptr + k0);
        uint4 bv = *(const uint4*)(Bptr + k0);
        __syncthreads();
        *(uint4*)&Asm[arow * 40 + aseg * 8] = av;
        *(uint4*)&Bsm[arow * 40 + aseg * 8] = bv;
        __syncthreads();
        short8v a0 = *(const short8v*)&Asm[(wrow * 32 + r16) * 40 + k8 * 8];
        short8v a1 = *(const short8v*)&Asm[(wrow * 32 + 16 + r16) * 40 + k8 * 8];
        short8v b0 = *(const short8v*)&Bsm[(wcol * 32 + r16) * 40 + k8 * 8];
        short8v b1 = *(const short8v*)&Bsm[(wcol * 32 + 16 + r16) * 40 + k8 * 8];
        acc[0][0] = __builtin_amdgcn_mfma_f32_16x16x32_bf16(a0, b0, acc[0][0], 0, 0, 0);
        acc[0][1] = __builtin_amdgcn_mfma_f32_16x16x32_bf16(a0, b1, acc[0][1], 0, 0, 0);
        acc[1][0] = __builtin_amdgcn_mfma_f32_16x16x32_bf16(a1, b0, acc[1][0], 0, 0, 0);
        acc[1][1] = __builtin_amdgcn_mfma_f32_16x16x32_bf16(a1, b1, acc[1][1], 0, 0, 0);
    }
    int q = lane >> 4;
    #pragma unroll
    for (int mi = 0; mi < 2; mi++)
    #pragma unroll
    for (int ni = 0; ni < 2; ni++) {
        int col = n0 + wcol * 32 + ni * 16 + r16;
        #pragma unroll
        for (int r = 0; r < 4; r++) {
            int row = m0 + wrow * 32 + mi * 16 + q * 4 + r;
            float v = acc[mi][ni][r];
            if (BIAS) v += bias[col];
            if (RES) v += resid[(size_t)row * Nn + col];
            if (GELU) v = 0.5f * v * (1.0f + erff(v * 0.70710678118654752f));
            if (OBF16) ((unsigned short*)Cout)[(size_t)row * Nn + col] = f2b(v);
            else       ((float*)Cout)[(size_t)row * Nn + col] = v;
        }
    }
}

// ---------------- window attention (MFMA, one wave per window-head) ----------
// qkv [M][576] bf16 (layout s*192 + head*32 + d), out ao [M][192] bf16
// S^T = mfma(K, Q):  C layout => col(lane&15)=i (query), row=(lane>>4)*4+r=j (key)
// => softmax over j is 16 lane-local values + shfl_xor(16), shfl_xor(32).
template<int SHIFT>
__global__ __launch_bounds__(128) void attn_k(const unsigned short* __restrict__ qkv,
                                              const float* __restrict__ pos,
                                              unsigned short* __restrict__ ao) {
    __shared__ float Pl[169];
    __shared__ unsigned short Pbuf[2][64 * 72];  // P[i][j] bf16, stride 72 (144B, 16B-aligned)
    __shared__ unsigned short Vtb[2][32 * 72];   // V^T[d][j]
    int t = threadIdx.x;
    int wid = t >> 6, lane = t & 63;
    int iq = lane & 15, hi = lane >> 4;
    int idx = blockIdx.x * 2 + wid;              // window-head id
    int window = idx / 6, head = idx % 6;
    int b = window >> 10, wrem = window & 1023;
    int wi = wrem >> 5, wj = wrem & 31;

    for (int ii = t; ii < 169; ii += 128) Pl[ii] = pos[ii];
    __syncthreads();

    unsigned short* P  = Pbuf[wid];
    unsigned short* Vt = Vtb[wid];

    auto trow = [&](int p) -> size_t {
        int pi = p / 7, pj = p - pi * 7;
        int gi = wi * 7 + pi, gj = wj * 7 + pj;
        if (SHIFT) { gi += DISPL; if (gi >= HH) gi -= HH; gj += DISPL; if (gj >= WWID) gj -= WWID; }
        return ((size_t)b * HH + gi) * WWID + gj;
    };

    // ---- stage V^T (lane l owns token l) ----
    if (lane < 49) {
        size_t m = trow(lane);
        const unsigned short* vsrc = qkv + m * 576 + 2 * 192 + head * 32;
        #pragma unroll
        for (int c = 0; c < 4; c++) {
            uint4 vv = *(const uint4*)(vsrc + c * 8);
            const unsigned short* us = (const unsigned short*)&vv;
            #pragma unroll
            for (int e = 0; e < 8; e++) Vt[(c * 8 + e) * 72 + lane] = us[e];
        }
    } else {
        #pragma unroll
        for (int d = 0; d < 32; d++) Vt[d * 72 + lane] = 0;
    }

    // ---- Q/K fragments direct from global (identical addressing for A and B)
    short8v aK[4], bQ[4];
    #pragma unroll
    for (int tt = 0; tt < 4; tt++) {
        int p = 16 * tt + iq;
        short8v zq = {0,0,0,0,0,0,0,0}, zk = zq;
        if (p < 49) {
            size_t m = trow(p);
            const unsigned short* base = qkv + m * 576 + head * 32 + hi * 8;
            zq = *(const short8v*)(base);
            zk = *(const short8v*)(base + 192);
        }
        aK[tt] = zk; bQ[tt] = zq;
    }

    f32x4 st[4][4] = {};   // [jt][it]
    #pragma unroll
    for (int jt = 0; jt < 4; jt++)
        #pragma unroll
        for (int it = 0; it < 4; it++)
            st[jt][it] = __builtin_amdgcn_mfma_f32_16x16x32_bf16(aK[jt], bQ[it], st[jt][it], 0, 0, 0);

    // ---- bias + mask + softmax (over j) + P -> LDS (bf16) ----
    const float scale = 0.17677669529663687f;
    #pragma unroll
    for (int it = 0; it < 4; it++) {
        int i = iq + 16 * it;
        int ic = i > 48 ? 48 : i;
        int ih = ic / 7, iw2 = ic - ih * 7;
        float sv[16];
        #pragma unroll
        for (int jt = 0; jt < 4; jt++) {
            #pragma unroll
            for (int r = 0; r < 4; r++) {
                int j = 16 * jt + 4 * hi + r;
                float s;
                if (j < 49) {
                    int jh = j / 7, jw2 = j - jh * 7;
                    s = st[jt][it][r] * scale + Pl[(jh - ih + 6) * 13 + (jw2 - iw2 + 6)];
                    if (SHIFT) {
                        bool msk = false;
                        if (wi == 31) msk = msk || ((i >= 28) != (j >= 28));
                        if (wj == 31) msk = msk || ((iw2 >= 4) != (jw2 >= 4));
                        if (msk) s = -1e30f;
                    }
                } else s = -1e30f;
                sv[jt * 4 + r] = s;
            }
        }
        float mx = sv[0];
        #pragma unroll
        for (int u = 1; u < 16; u++) mx = fmaxf(mx, sv[u]);
        mx = fmaxf(mx, __shfl_xor(mx, 16));
        mx = fmaxf(mx, __shfl_xor(mx, 32));
        float sum = 0.f;
        #pragma unroll
        for (int u = 0; u < 16; u++) { sv[u] = __expf(sv[u] - mx); sum += sv[u]; }
        sum += __shfl_xor(sum, 16);
        sum += __shfl_xor(sum, 32);
        float rinv = 1.0f / sum;
        #pragma unroll
        for (int jt = 0; jt < 4; jt++) {
            ushort4 w4;
            w4.x = f2b(sv[jt * 4 + 0] * rinv);
            w4.y = f2b(sv[jt * 4 + 1] * rinv);
            w4.z = f2b(sv[jt * 4 + 2] * rinv);
            w4.w = f2b(sv[jt * 4 + 3] * rinv);
            *(ushort4*)&P[i * 72 + 16 * jt + 4 * hi] = w4;
        }
    }

    // ---- PV: out[i][d] = sum_j P[i][j] V[j][d] ----
    f32x4 o[4][2] = {};
    #pragma unroll
    for (int ks = 0; ks < 2; ks++) {
        short8v bV[2], aP[4];
        #pragma unroll
        for (int nt = 0; nt < 2; nt++)
            bV[nt] = *(const short8v*)&Vt[(iq + 16 * nt) * 72 + 32 * ks + 8 * hi];
        #pragma unroll
        for (int mt = 0; mt < 4; mt++)
            aP[mt] = *(const short8v*)&P[(iq + 16 * mt) * 72 + 32 * ks + 8 * hi];
        #pragma unroll
        for (int mt = 0; mt < 4; mt++)
            #pragma unroll
            for (int nt = 0; nt < 2; nt++)
                o[mt][nt] = __builtin_amdgcn_mfma_f32_16x16x32_bf16(aP[mt], bV[nt], o[mt][nt], 0, 0, 0);
    }

    // ---- store: frag col d = iq + 16nt, row i = 16mt + 4hi + r ----
    #pragma unroll
    for (int mt = 0; mt < 4; mt++) {
        #pragma unroll
        for (int r = 0; r < 4; r++) {
            int i = 16 * mt + 4 * hi + r;
            if (i < 49) {
                size_t m = trow(i);
                unsigned short* dst = ao + m * 192 + head * 32 + iq;
                dst[0]  = f2b(o[mt][0][r]);
                dst[16] = f2b(o[mt][1][r]);
            }
        }
    }
}

// ---------------- final transpose: t[2][224][224][192] -> out[2][192][224][224]
__global__ __launch_bounds__(256) void tr_k(const float* __restrict__ tin,
                                            float* __restrict__ outp) {
    __shared__ float tile[32][33];
    int bi = blockIdx.x;                  // b*224 + i
    int j0 = blockIdx.y * 32, c0 = blockIdx.z * 32;
    int t = threadIdx.x;
    int tx = t & 31, ty = t >> 5;
    int b = bi / 224, i = bi % 224;
    #pragma unroll
    for (int yy = 0; yy < 32; yy += 8) {
        int j = j0 + ty + yy;
        tile[ty + yy][tx] = tin[((size_t)bi * 224 + j) * 192 + c0 + tx];
    }
    __syncthreads();
    #pragma unroll
    for (int yy = 0; yy < 32; yy += 8) {
        int c = c0 + ty + yy;
        outp[(((size_t)b * 192 + c) * 224 + i) * 224 + j0 + tx] = tile[tx][ty + yy];
    }
}

extern "C" void kernel_launch(void* const* d_in, const int* in_sizes, int n_in,
                              void* d_out, int out_size, void* d_ws, size_t ws_size,
                              hipStream_t stream) {
    (void)in_sizes; (void)n_in; (void)out_size; (void)ws_size;
    const float* x    = (const float*)d_in[0];
    const float* pm_w = (const float*)d_in[1];
    const float* pm_b = (const float*)d_in[2];

    const size_t M = MROWS;
    char* ws = (char*)d_ws;
    size_t off = 0;
    float* tbuf = (float*)(ws + off);           off += M * 192 * 4;   // 77.07 MB
    unsigned short* ybuf = (unsigned short*)(ws + off); off += M * 192 * 2; // 38.5 MB
    unsigned short* big  = (unsigned short*)(ws + off); off += M * 768 * 2; // 154 MB (U / qkv / h)
    unsigned short* pm_wt = (unsigned short*)(ws + off); off += 192 * 384 * 2;
    unsigned short* wqkv_t[2]; unsigned short* wo_t[2];
    unsigned short* w1_t[2];   unsigned short* w2_t[2];
    for (int s = 0; s < 2; s++) {
        wqkv_t[s] = (unsigned short*)(ws + off); off += 576 * 192 * 2;
        wo_t[s]   = (unsigned short*)(ws + off); off += 192 * 192 * 2;
        w1_t[s]   = (unsigned short*)(ws + off); off += 768 * 192 * 2;
        w2_t[s]   = (unsigned short*)(ws + off); off += 192 * 768 * 2;
    }
    unsigned short* U   = big;              // [M][384]
    unsigned short* qkv = big;              // [M][576]
    unsigned short* hbf = big;              // [M][768]
    unsigned short* ao  = ybuf;             // aliases y (y dead when attn writes)

    auto wt = [&](const float* W, unsigned short* Wt, int K, int N) {
        int n = K * N;
        wt_k<<<(n + 255) / 256, 256, 0, stream>>>(W, Wt, K, N);
    };
    wt(pm_w, pm_wt, 384, 192);
    for (int s = 0; s < 2; s++) {
        wt((const float*)d_in[5 + 12 * s],  wqkv_t[s], 192, 576);
        wt((const float*)d_in[7 + 12 * s],  wo_t[s],   192, 192);
        wt((const float*)d_in[11 + 12 * s], w1_t[s],   192, 768);
        wt((const float*)d_in[13 + 12 * s], w2_t[s],   768, 192);
    }

    unfold_k<<<NB * 224 * 4, 192, 0, stream>>>(x, U);
    // t = U @ pm_w + pm_b
    gemm_k<1, 0, 0, 0><<<dim3(3, MROWS / 64), 256, 0, stream>>>(U, pm_wt, pm_b, nullptr, tbuf, 192, 384);

    for (int s = 0; s < 2; s++) {
        const float* ln1g = (const float*)d_in[3 + 12 * s];
        const float* ln1b = (const float*)d_in[4 + 12 * s];
        const float* pos  = (const float*)d_in[6 + 12 * s];
        const float* bo   = (const float*)d_in[8 + 12 * s];
        const float* ln2g = (const float*)d_in[9 + 12 * s];
        const float* ln2b = (const float*)d_in[10 + 12 * s];
        const float* b1   = (const float*)d_in[12 + 12 * s];
        const float* b2   = (const float*)d_in[14 + 12 * s];

        ln_k<<<MROWS / 4, 256, 0, stream>>>(tbuf, ln1g, ln1b, ybuf);
        gemm_k<0, 0, 0, 1><<<dim3(9, MROWS / 64), 256, 0, stream>>>(ybuf, wqkv_t[s], nullptr, nullptr, qkv, 576, 192);
        if (s == 0) attn_k<0><<<2048 * NHEADS / 2, 128, 0, stream>>>(qkv, pos, ao);
        else        attn_k<1><<<2048 * NHEADS / 2, 128, 0, stream>>>(qkv, pos, ao);
        gemm_k<1, 1, 0, 0><<<dim3(3, MROWS / 64), 256, 0, stream>>>(ao, wo_t[s], bo, tbuf, tbuf, 192, 192);
        ln_k<<<MROWS / 4, 256, 0, stream>>>(tbuf, ln2g, ln2b, ybuf);
        gemm_k<1, 0, 1, 1><<<dim3(12, MROWS / 64), 256, 0, stream>>>(ybuf, w1_t[s], b1, nullptr, hbf, 768, 192);
        gemm_k<1, 1, 0, 0><<<dim3(3, MROWS / 64), 256, 0, stream>>>(hbf, w2_t[s], b2, tbuf, tbuf, 192, 768);
    }

    tr_k<<<dim3(NB * 224, 7, 6), 256, 0, stream>>>(tbuf, (float*)d_out);
}